// Round 6
// baseline (629.605 us; speedup 1.0000x reference)
//
#include <hip/hip_runtime.h>

// Problem constants
#define CI   16
#define CO   32
#define COH  16              // channels per block (c_out split across 2 blocks)
#define IND  34
#define INH  66
#define INW  66
#define CHS  (IND*INH*INW)   // 148104 floats per (b,ci) channel
#define ZS   (INH*INW)       // 4356
#define NW   13824           // CO*CI*27 weight elements
#define TILE_ELEMS 2376      // 6*6*66 staged input floats per ci (full width)
#define TILE_V2    1188      // as float2

// ---------------------------------------------------------------------------
// Re-layout weights [co][ci][kd][kh][kw] -> [ci][tap][co]: the conv kernel
// reads 48 consecutive wave-uniform dwords per (ci,kd,kh) -> scalarizable to
// s_load (SGPR_Count=112 @r5 corroborates); weights then ride the FMA's
// single allowed SGPR operand.
// ---------------------------------------------------------------------------
__global__ void wtrans_kernel(const float* __restrict__ w, float* __restrict__ wt) {
    int i = blockIdx.x * 256 + threadIdx.x;
    if (i < NW) {
        int co  = i / (CI * 27);
        int r   = i % (CI * 27);
        int ci  = r / 27;
        int tap = r % 27;
        wt[(ci * 27 + tap) * CO + co] = w[i];
    }
}

// ---------------------------------------------------------------------------
// out[b] = 0.5*sum(pooled maxes of raw conv) + sum_c( 8192*conv_bias[c] + bias[c] )
// (conv_bias commutes with max; 16384 pooled elems per (b,c) x 0.5 = 8192.)
// d_out is re-poisoned before every timed launch, so this runs every call.
// ---------------------------------------------------------------------------
__global__ void init_out_kernel(const float* __restrict__ conv_bias,
                                const float* __restrict__ bias,
                                float* __restrict__ out) {
    int l = threadIdx.x;           // 64 threads, one wave
    float v = 0.f;
    if (l < CO) v = 8192.0f * conv_bias[l] + bias[l];
    #pragma unroll
    for (int off = 32; off > 0; off >>= 1) v += __shfl_xor(v, off);
    if (l < 8) out[l] = v;         // all lanes hold the full sum
}

// ---------------------------------------------------------------------------
// Fused conv3d + 2x2x2 maxpool + channel/spatial sum.
// Grid: (16 h-tiles, 64 = b*8 + d-tile, 2 co-halves). Block: 256 threads.
// Tile: 4(d) x 4(h) x 64(w) x 16(co). Thread t owns a w-QUAD for 16 channels:
// 64 fp32 accumulators.
// REGISTER HISTORY: r3 (256,2): 128 accums -> 120 VGPR + AGPR split, 1163us.
//                   r5 (256,4): 64 accums -> VGPR capped at 64, ~40 regs
//                   spilled to scratch (WRITE_SIZE 275 MB!), 565us.
//                   r6 (256,2): cap >=128, live set ~105 -> no spill, no AGPR.
// Thread mapping: t = wp(b0-3) | dd0(b4) | hh0(b5) | dd1(b6) | hh1(b7)
//   => both pool partners are in-wave: d-pair = shfl_xor 16, h-pair = 32.
// LDS = 2*2376*4B = 19 KB. Bank conflicts measured ~4%/CU cycles - hidden
// under the FMA pipe (ds_read latency covered by 12-FMA-deep reuse).
// ---------------------------------------------------------------------------
__global__ void __launch_bounds__(256, 2)
conv_pool_kernel(const float* __restrict__ x,
                 const float* __restrict__ wt,
                 float* __restrict__ out) {
    __shared__ float buf[2][TILE_ELEMS];   // double-buffered per-ci input tile
    __shared__ float wsum[4];

    const int t  = threadIdx.x;
    const int wp = t & 15;
    const int dd = ((t >> 4) & 1) | ((t >> 5) & 2);   // bit4 -> dd0, bit6 -> dd1
    const int hh = ((t >> 5) & 1) | ((t >> 6) & 2);   // bit5 -> hh0, bit7 -> hh1

    const int htile = blockIdx.x;          // 0..15
    const int b     = blockIdx.y >> 3;     // 0..7
    const int dtile = blockIdx.y & 7;      // 0..7
    const int co0   = blockIdx.z * COH;    // 0 or 16

    const int z0 = dtile * 4, y0 = htile * 4;

    // float2 staging: slot k covers float2-index (t + k*256) of the 6x6x66
    // tile; only the global-side offsets need registers (division-derived).
    // All offsets are even -> 8B alignment on both sides; rows are 66 floats
    // so no float2 straddles a row.
    int goff2[5];
    #pragma unroll
    for (int k = 0; k < 5; ++k) {
        int f = 2 * (t + k * 256);
        int z = f / 396;        // 396 = 6*66
        int r = f % 396;
        int y = r / 66;
        int xx = r % 66;
        goff2[k] = z * ZS + y * INW + xx;   // even
    }
    const bool tail = (t + 4 * 256) < TILE_V2;   // k=4 slot valid?
    const size_t base0 = (size_t)(b * CI) * CHS + (size_t)z0 * ZS
                       + (size_t)y0 * INW;            // even

    float a0[COH], a1[COH], a2[COH], a3[COH];
    #pragma unroll
    for (int co = 0; co < COH; ++co) { a0[co] = 0.f; a1[co] = 0.f; a2[co] = 0.f; a3[co] = 0.f; }

    // Prologue: stage ci=0 into buf[0]
    {
        const float* g = x + base0;
        float2* b2 = (float2*)&buf[0][0];
        #pragma unroll
        for (int k = 0; k < 4; ++k)
            b2[t + k * 256] = *(const float2*)(g + goff2[k]);
        if (tail) b2[t + 4 * 256] = *(const float2*)(g + goff2[4]);
    }

    // ci loop NOT unrolled (x16 unroll would blow the 32KB I-cache).
    #pragma unroll 1
    for (int ci = 0; ci < CI; ++ci) {
        __syncthreads();                    // buf[ci&1] staged; other half free
        const int cur = ci & 1;

        // Software pipeline: next channel's global loads -> registers; their
        // latency hides under the 1728 FMAs below.
        float2 r0, r1, r2, r3, r4;
        const bool pre = (ci + 1 < CI);
        if (pre) {
            const float* g = x + base0 + (size_t)(ci + 1) * CHS;
            r0 = *(const float2*)(g + goff2[0]);
            r1 = *(const float2*)(g + goff2[1]);
            r2 = *(const float2*)(g + goff2[2]);
            r3 = *(const float2*)(g + goff2[3]);
            r4 = tail ? *(const float2*)(g + goff2[4]) : make_float2(0.f, 0.f);
        }

        const float* cb = buf[cur];
        const float* __restrict__ wbase = wt + ci * 27 * CO + co0;
        #pragma unroll
        for (int kd = 0; kd < 3; ++kd)
        #pragma unroll
        for (int kh = 0; kh < 3; ++kh) {
            const float* row = &cb[((dd + kd) * 6 + (hh + kh)) * 66 + 4 * wp];
            float x0v = row[0], x1v = row[1], x2v = row[2],
                  x3v = row[3], x4v = row[4], x5v = row[5];
            const float* __restrict__ wr = wbase + (kd * 9 + kh * 3) * CO; // uniform
            #pragma unroll
            for (int co = 0; co < COH; ++co) {
                float w0 = wr[co], w1 = wr[CO + co], w2 = wr[2 * CO + co];
                a0[co] = fmaf(x0v, w0, a0[co]);
                a0[co] = fmaf(x1v, w1, a0[co]);
                a0[co] = fmaf(x2v, w2, a0[co]);
                a1[co] = fmaf(x1v, w0, a1[co]);
                a1[co] = fmaf(x2v, w1, a1[co]);
                a1[co] = fmaf(x3v, w2, a1[co]);
                a2[co] = fmaf(x2v, w0, a2[co]);
                a2[co] = fmaf(x3v, w1, a2[co]);
                a2[co] = fmaf(x4v, w2, a2[co]);
                a3[co] = fmaf(x3v, w0, a3[co]);
                a3[co] = fmaf(x4v, w1, a3[co]);
                a3[co] = fmaf(x5v, w2, a3[co]);
            }
        }

        if (pre) {
            float2* nb = (float2*)&buf[cur ^ 1][0];
            nb[t + 0 * 256] = r0; nb[t + 1 * 256] = r1;
            nb[t + 2 * 256] = r2; nb[t + 3 * 256] = r3;
            if (tail) nb[t + 4 * 256] = r4;
        }
    }

    // ---- fused 2x2x2 maxpool + sum, entirely via in-wave shuffles ----
    float psum = 0.f;
    #pragma unroll
    for (int co = 0; co < COH; ++co) {
        float m0 = fmaxf(a0[co], a1[co]);
        float m1 = fmaxf(a2[co], a3[co]);
        m0 = fmaxf(m0, __shfl_xor(m0, 16));  // d-pool
        m1 = fmaxf(m1, __shfl_xor(m1, 16));
        m0 = fmaxf(m0, __shfl_xor(m0, 32));  // h-pool
        m1 = fmaxf(m1, __shfl_xor(m1, 32));
        psum += m0 + m1;
    }
    if ((t & 48) != 0) psum = 0.f;           // one owner per 2x2x2 block

    // block reduction -> one atomic per block
    #pragma unroll
    for (int off = 1; off < 64; off <<= 1) psum += __shfl_xor(psum, off);
    if ((t & 63) == 0) wsum[t >> 6] = psum;
    __syncthreads();
    if (t == 0) {
        float tot = (wsum[0] + wsum[1]) + (wsum[2] + wsum[3]);
        atomicAdd(&out[b], 0.5f * tot);
    }
}

// ---------------------------------------------------------------------------
extern "C" void kernel_launch(void* const* d_in, const int* in_sizes, int n_in,
                              void* d_out, int out_size, void* d_ws, size_t ws_size,
                              hipStream_t stream) {
    const float* x         = (const float*)d_in[0];
    const float* conv_w    = (const float*)d_in[1];
    const float* conv_bias = (const float*)d_in[2];
    const float* bias      = (const float*)d_in[3];
    float* out = (float*)d_out;
    float* wtb = (float*)d_ws;              // 13824 floats = 55.3 KB scratch

    wtrans_kernel<<<(NW + 255) / 256, 256, 0, stream>>>(conv_w, wtb);
    init_out_kernel<<<1, 64, 0, stream>>>(conv_bias, bias, out);
    conv_pool_kernel<<<dim3(16, 64, 2), 256, 0, stream>>>(x, wtb, out);
}

// Round 10
// 500.342 us; speedup vs baseline: 1.2583x; 1.2583x over previous
//
#include <hip/hip_runtime.h>

// Problem constants
#define CI   16
#define CO   32
#define COH  8               // channels per block (c_out split across 4 blocks)
#define IND  34
#define INH  66
#define INW  66
#define CHS  (IND*INH*INW)   // 148104 floats per (b,ci) channel
#define ZS   (INH*INW)       // 4356
#define NW   13824           // CO*CI*27 weight elements
#define TILE_ELEMS 2376      // 6*6*66 staged input floats per ci (full width)
#define TILE_V2    1188      // as float2

// ---------------------------------------------------------------------------
// Re-layout weights [co][ci][kd][kh][kw] -> [ci][tap][co]: the conv kernel
// reads 24 consecutive wave-uniform dwords per (ci,kd,kh) -> scalarizable to
// s_load (SGPR_Count=112 @r5/r6 corroborates); weights then ride the FMA's
// single allowed SGPR operand.
// ---------------------------------------------------------------------------
__global__ void wtrans_kernel(const float* __restrict__ w, float* __restrict__ wt) {
    int i = blockIdx.x * 256 + threadIdx.x;
    if (i < NW) {
        int co  = i / (CI * 27);
        int r   = i % (CI * 27);
        int ci  = r / 27;
        int tap = r % 27;
        wt[(ci * 27 + tap) * CO + co] = w[i];
    }
}

// ---------------------------------------------------------------------------
// out[b] = 0.5*sum(pooled maxes of raw conv) + sum_c( 8192*conv_bias[c] + bias[c] )
// (conv_bias commutes with max; 16384 pooled elems per (b,c) x 0.5 = 8192.)
// d_out is re-poisoned before every timed launch, so this runs every call.
// ---------------------------------------------------------------------------
__global__ void init_out_kernel(const float* __restrict__ conv_bias,
                                const float* __restrict__ bias,
                                float* __restrict__ out) {
    int l = threadIdx.x;           // 64 threads, one wave
    float v = 0.f;
    if (l < CO) v = 8192.0f * conv_bias[l] + bias[l];
    #pragma unroll
    for (int off = 32; off > 0; off >>= 1) v += __shfl_xor(v, off);
    if (l < 8) out[l] = v;         // all lanes hold the full sum
}

// ---------------------------------------------------------------------------
// Fused conv3d + 2x2x2 maxpool + channel/spatial sum.
// Grid: (16 h-tiles, 64 = b*8 + d-tile, 4 co-quarters). Block: 256 threads.
// Tile: 4(d) x 4(h) x 64(w) x 8(co). Thread t owns a w-QUAD for 8 channels:
// 32 fp32 accumulators.
// REGISTER HISTORY: r3: 128 accums -> 120 VGPR + AGPR shuttle, 1163us.
//   r5 (256,4): 64 accums -> VGPR capped 64, scratch spill (WRITE 275MB), 565us.
//   r6 (256,2): 64 accums -> 92 VGPR but occupancy 23% + VALU 2x FMA-floor
//     => compiler parked accums in AGPRs (accvgpr shuttles), 571us.
//   r7: 32 accums, live set ~70 regs -> no pressure at all; occupancy is the
//     discriminating counter (predict 55-75%; ~25% falsifies AGPR theory).
// Thread mapping: t = wp(b0-3) | dd0(b4) | hh0(b5) | dd1(b6) | hh1(b7)
//   => both pool partners are in-wave: d-pair = shfl_xor 16, h-pair = 32.
// LDS = 2*2376*4B = 19 KB -> 6+ blocks/CU fit (VGPR-limited ~6 waves/SIMD).
// ---------------------------------------------------------------------------
__global__ void __launch_bounds__(256, 2)
conv_pool_kernel(const float* __restrict__ x,
                 const float* __restrict__ wt,
                 float* __restrict__ out) {
    __shared__ float buf[2][TILE_ELEMS];   // double-buffered per-ci input tile
    __shared__ float wsum[4];

    const int t  = threadIdx.x;
    const int wp = t & 15;
    const int dd = ((t >> 4) & 1) | ((t >> 5) & 2);   // bit4 -> dd0, bit6 -> dd1
    const int hh = ((t >> 5) & 1) | ((t >> 6) & 2);   // bit5 -> hh0, bit7 -> hh1

    const int htile = blockIdx.x;          // 0..15
    const int b     = blockIdx.y >> 3;     // 0..7
    const int dtile = blockIdx.y & 7;      // 0..7
    const int co0   = blockIdx.z * COH;    // 0,8,16,24

    const int z0 = dtile * 4, y0 = htile * 4;

    // float2 staging: slot k covers float2-index (t + k*256) of the 6x6x66
    // tile. All offsets even -> 8B alignment on both sides; rows are 66
    // floats so no float2 straddles a row.
    int goff2[5];
    #pragma unroll
    for (int k = 0; k < 5; ++k) {
        int f = 2 * (t + k * 256);
        int z = f / 396;        // 396 = 6*66
        int r = f % 396;
        int y = r / 66;
        int xx = r % 66;
        goff2[k] = z * ZS + y * INW + xx;   // even
    }
    const bool tail = (t + 4 * 256) < TILE_V2;   // k=4 slot valid?
    const size_t base0 = (size_t)(b * CI) * CHS + (size_t)z0 * ZS
                       + (size_t)y0 * INW;            // even

    float a0[COH], a1[COH], a2[COH], a3[COH];
    #pragma unroll
    for (int co = 0; co < COH; ++co) { a0[co] = 0.f; a1[co] = 0.f; a2[co] = 0.f; a3[co] = 0.f; }

    // Prologue: stage ci=0 into buf[0]
    {
        const float* g = x + base0;
        float2* b2 = (float2*)&buf[0][0];
        #pragma unroll
        for (int k = 0; k < 4; ++k)
            b2[t + k * 256] = *(const float2*)(g + goff2[k]);
        if (tail) b2[t + 4 * 256] = *(const float2*)(g + goff2[4]);
    }

    // ci loop NOT unrolled (x16 unroll would blow the 32KB I-cache).
    #pragma unroll 1
    for (int ci = 0; ci < CI; ++ci) {
        __syncthreads();                    // buf[ci&1] staged; other half free
        const int cur = ci & 1;

        // Software pipeline: next channel's global loads -> registers; their
        // latency hides under the 864 FMAs below.
        float2 r0, r1, r2, r3, r4;
        const bool pre = (ci + 1 < CI);
        if (pre) {
            const float* g = x + base0 + (size_t)(ci + 1) * CHS;
            r0 = *(const float2*)(g + goff2[0]);
            r1 = *(const float2*)(g + goff2[1]);
            r2 = *(const float2*)(g + goff2[2]);
            r3 = *(const float2*)(g + goff2[3]);
            r4 = tail ? *(const float2*)(g + goff2[4]) : make_float2(0.f, 0.f);
        }

        const float* cb = buf[cur];
        const float* __restrict__ wbase = wt + ci * 27 * CO + co0;
        #pragma unroll
        for (int kd = 0; kd < 3; ++kd)
        #pragma unroll
        for (int kh = 0; kh < 3; ++kh) {
            const float* row = &cb[((dd + kd) * 6 + (hh + kh)) * 66 + 4 * wp];
            float x0v = row[0], x1v = row[1], x2v = row[2],
                  x3v = row[3], x4v = row[4], x5v = row[5];
            const float* __restrict__ wr = wbase + (kd * 9 + kh * 3) * CO; // uniform
            #pragma unroll
            for (int co = 0; co < COH; ++co) {
                float w0 = wr[co], w1 = wr[CO + co], w2 = wr[2 * CO + co];
                a0[co] = fmaf(x0v, w0, a0[co]);
                a0[co] = fmaf(x1v, w1, a0[co]);
                a0[co] = fmaf(x2v, w2, a0[co]);
                a1[co] = fmaf(x1v, w0, a1[co]);
                a1[co] = fmaf(x2v, w1, a1[co]);
                a1[co] = fmaf(x3v, w2, a1[co]);
                a2[co] = fmaf(x2v, w0, a2[co]);
                a2[co] = fmaf(x3v, w1, a2[co]);
                a2[co] = fmaf(x4v, w2, a2[co]);
                a3[co] = fmaf(x3v, w0, a3[co]);
                a3[co] = fmaf(x4v, w1, a3[co]);
                a3[co] = fmaf(x5v, w2, a3[co]);
            }
        }

        if (pre) {
            float2* nb = (float2*)&buf[cur ^ 1][0];
            nb[t + 0 * 256] = r0; nb[t + 1 * 256] = r1;
            nb[t + 2 * 256] = r2; nb[t + 3 * 256] = r3;
            if (tail) nb[t + 4 * 256] = r4;
        }
    }

    // ---- fused 2x2x2 maxpool + sum, entirely via in-wave shuffles ----
    float psum = 0.f;
    #pragma unroll
    for (int co = 0; co < COH; ++co) {
        float m0 = fmaxf(a0[co], a1[co]);
        float m1 = fmaxf(a2[co], a3[co]);
        m0 = fmaxf(m0, __shfl_xor(m0, 16));  // d-pool
        m1 = fmaxf(m1, __shfl_xor(m1, 16));
        m0 = fmaxf(m0, __shfl_xor(m0, 32));  // h-pool
        m1 = fmaxf(m1, __shfl_xor(m1, 32));
        psum += m0 + m1;
    }
    if ((t & 48) != 0) psum = 0.f;           // one owner per 2x2x2 block

    // block reduction -> one atomic per block
    #pragma unroll
    for (int off = 1; off < 64; off <<= 1) psum += __shfl_xor(psum, off);
    if ((t & 63) == 0) wsum[t >> 6] = psum;
    __syncthreads();
    if (t == 0) {
        float tot = (wsum[0] + wsum[1]) + (wsum[2] + wsum[3]);
        atomicAdd(&out[b], 0.5f * tot);
    }
}

// ---------------------------------------------------------------------------
extern "C" void kernel_launch(void* const* d_in, const int* in_sizes, int n_in,
                              void* d_out, int out_size, void* d_ws, size_t ws_size,
                              hipStream_t stream) {
    const float* x         = (const float*)d_in[0];
    const float* conv_w    = (const float*)d_in[1];
    const float* conv_bias = (const float*)d_in[2];
    const float* bias      = (const float*)d_in[3];
    float* out = (float*)d_out;
    float* wtb = (float*)d_ws;              // 13824 floats = 55.3 KB scratch

    wtrans_kernel<<<(NW + 255) / 256, 256, 0, stream>>>(conv_w, wtb);
    init_out_kernel<<<1, 64, 0, stream>>>(conv_bias, bias, out);
    conv_pool_kernel<<<dim3(16, 64, 4), 256, 0, stream>>>(x, wtb, out);
}

// Round 13
// 364.119 us; speedup vs baseline: 1.7291x; 1.3741x over previous
//
#include <hip/hip_runtime.h>

// Problem constants
#define CI   16
#define CO   32
#define COH  8               // channels per block (c_out split across 4 blocks)
#define IND  34
#define INH  66
#define INW  66
#define CHS  (IND*INH*INW)   // 148104 floats per (b,ci) channel
#define ZS   (INH*INW)       // 4356
#define NW   13824           // CO*CI*27 weight elements
#define TILE_ELEMS 2376      // 6*6*66 staged input floats per ci (full width)
#define TILE_V2    1188      // as float2

// ---------------------------------------------------------------------------
// Re-layout weights [co][ci][kd][kh][kw] -> [ci][tap][co]: the conv kernel
// reads 24 consecutive wave-uniform dwords per (ci,kd,kh) -> scalarizable to
// s_load (SGPR_Count=112 corroborates); weights then ride the FMA's single
// allowed SGPR operand.
// ---------------------------------------------------------------------------
__global__ void wtrans_kernel(const float* __restrict__ w, float* __restrict__ wt) {
    int i = blockIdx.x * 256 + threadIdx.x;
    if (i < NW) {
        int co  = i / (CI * 27);
        int r   = i % (CI * 27);
        int ci  = r / 27;
        int tap = r % 27;
        wt[(ci * 27 + tap) * CO + co] = w[i];
    }
}

// ---------------------------------------------------------------------------
// out[b] = 0.5*sum(pooled maxes of raw conv) + sum_c( 8192*conv_bias[c] + bias[c] )
// (conv_bias commutes with max; 16384 pooled elems per (b,c) x 0.5 = 8192.)
// d_out is re-poisoned before every timed launch, so this runs every call.
// ---------------------------------------------------------------------------
__global__ void init_out_kernel(const float* __restrict__ conv_bias,
                                const float* __restrict__ bias,
                                float* __restrict__ out) {
    int l = threadIdx.x;           // 64 threads, one wave
    float v = 0.f;
    if (l < CO) v = 8192.0f * conv_bias[l] + bias[l];
    #pragma unroll
    for (int off = 32; off > 0; off >>= 1) v += __shfl_xor(v, off);
    if (l < 8) out[l] = v;         // all lanes hold the full sum
}

// ---------------------------------------------------------------------------
// Fused conv3d + 2x2x2 maxpool + channel/spatial sum.
// Grid: (16 h-tiles, 64 = b*8 + d-tile, 4 co-quarters). Block: 256 threads.
// Tile: 4(d) x 4(h) x 64(w) x 8(co). Thread t owns a w-QUAD for 8 channels:
// 32 fp32 accumulators.
// REGISTER/SCHEDULING HISTORY:
//   r3: 128 accums -> 120 VGPR + AGPR shuttle, 1163us.
//   r5 (256,4): 64 accums -> VGPR capped 64, scratch spill (WRITE 275MB), 565us.
//   r6 (256,2): 64 accums -> VGPR 60 + 32? AGPR, occ 23%, VALU 2x floor, 571us.
//   r10: 32 accums -> STILL VGPR=60 + accums in AGPRs (shuttle ~0.85 VALU/FMA,
//        VALU-time 340us vs 184 floor), occ 40%, 450us. Diagnosis: the fully
//        unrolled 864-FMA body lets the scheduler hoist LDS reads, blowing the
//        ~64-arch-VGPR target -> allocator parks accums in AGPRs (gfx908-era
//        "free" heuristic; NOT free on gfx950's unified file).
//   r11/r12 (this): #pragma unroll 1 on kd -> 3x smaller scheduling window
//        (288 FMAs, 9 ds_read, ~80 live). Discriminator: VGPR_Count should
//        jump to ~96-120 (accums in arch file); if it stays ~60, the window
//        theory is falsified.
// Thread mapping: t = wp(b0-3) | dd0(b4) | hh0(b5) | dd1(b6) | hh1(b7)
//   => both pool partners are in-wave: d-pair = shfl_xor 16, h-pair = 32.
// LDS = 2*2376*4B = 19 KB. Bank conflicts ~10% of wall cycles (26.7M @r10)
// -- secondary; revisit only if VALU saturates.
// ---------------------------------------------------------------------------
__global__ void __launch_bounds__(256, 2)
conv_pool_kernel(const float* __restrict__ x,
                 const float* __restrict__ wt,
                 float* __restrict__ out) {
    __shared__ float buf[2][TILE_ELEMS];   // double-buffered per-ci input tile
    __shared__ float wsum[4];

    const int t  = threadIdx.x;
    const int wp = t & 15;
    const int dd = ((t >> 4) & 1) | ((t >> 5) & 2);   // bit4 -> dd0, bit6 -> dd1
    const int hh = ((t >> 5) & 1) | ((t >> 6) & 2);   // bit5 -> hh0, bit7 -> hh1

    const int htile = blockIdx.x;          // 0..15
    const int b     = blockIdx.y >> 3;     // 0..7
    const int dtile = blockIdx.y & 7;      // 0..7
    const int co0   = blockIdx.z * COH;    // 0,8,16,24

    const int z0 = dtile * 4, y0 = htile * 4;

    // float2 staging: slot k covers float2-index (t + k*256) of the 6x6x66
    // tile. All offsets even -> 8B alignment on both sides; rows are 66
    // floats so no float2 straddles a row.
    int goff2[5];
    #pragma unroll
    for (int k = 0; k < 5; ++k) {
        int f = 2 * (t + k * 256);
        int z = f / 396;        // 396 = 6*66
        int r = f % 396;
        int y = r / 66;
        int xx = r % 66;
        goff2[k] = z * ZS + y * INW + xx;   // even
    }
    const bool tail = (t + 4 * 256) < TILE_V2;   // k=4 slot valid?
    const size_t base0 = (size_t)(b * CI) * CHS + (size_t)z0 * ZS
                       + (size_t)y0 * INW;            // even

    float a0[COH], a1[COH], a2[COH], a3[COH];
    #pragma unroll
    for (int co = 0; co < COH; ++co) { a0[co] = 0.f; a1[co] = 0.f; a2[co] = 0.f; a3[co] = 0.f; }

    // Prologue: stage ci=0 into buf[0]
    {
        const float* g = x + base0;
        float2* b2 = (float2*)&buf[0][0];
        #pragma unroll
        for (int k = 0; k < 4; ++k)
            b2[t + k * 256] = *(const float2*)(g + goff2[k]);
        if (tail) b2[t + 4 * 256] = *(const float2*)(g + goff2[4]);
    }

    // ci loop NOT unrolled (x16 unroll would blow the 32KB I-cache).
    #pragma unroll 1
    for (int ci = 0; ci < CI; ++ci) {
        __syncthreads();                    // buf[ci&1] staged; other half free
        const int cur = ci & 1;

        // Software pipeline: next channel's global loads -> registers; their
        // latency hides under the 864 FMAs below.
        float2 r0, r1, r2, r3, r4;
        const bool pre = (ci + 1 < CI);
        if (pre) {
            const float* g = x + base0 + (size_t)(ci + 1) * CHS;
            r0 = *(const float2*)(g + goff2[0]);
            r1 = *(const float2*)(g + goff2[1]);
            r2 = *(const float2*)(g + goff2[2]);
            r3 = *(const float2*)(g + goff2[3]);
            r4 = tail ? *(const float2*)(g + goff2[4]) : make_float2(0.f, 0.f);
        }

        const float* cb = buf[cur];
        const float* __restrict__ wbase = wt + ci * 27 * CO + co0;
        // kd NOT unrolled (r11 fix): keep the scheduling window at 288 FMAs
        // so hoisted LDS reads + accums fit the arch-VGPR file (no AGPR park).
        #pragma unroll 1
        for (int kd = 0; kd < 3; ++kd) {
            #pragma unroll
            for (int kh = 0; kh < 3; ++kh) {
                const float* row = &cb[((dd + kd) * 6 + (hh + kh)) * 66 + 4 * wp];
                float x0v = row[0], x1v = row[1], x2v = row[2],
                      x3v = row[3], x4v = row[4], x5v = row[5];
                const float* __restrict__ wr = wbase + (kd * 9 + kh * 3) * CO; // uniform
                #pragma unroll
                for (int co = 0; co < COH; ++co) {
                    float w0 = wr[co], w1 = wr[CO + co], w2 = wr[2 * CO + co];
                    a0[co] = fmaf(x0v, w0, a0[co]);
                    a0[co] = fmaf(x1v, w1, a0[co]);
                    a0[co] = fmaf(x2v, w2, a0[co]);
                    a1[co] = fmaf(x1v, w0, a1[co]);
                    a1[co] = fmaf(x2v, w1, a1[co]);
                    a1[co] = fmaf(x3v, w2, a1[co]);
                    a2[co] = fmaf(x2v, w0, a2[co]);
                    a2[co] = fmaf(x3v, w1, a2[co]);
                    a2[co] = fmaf(x4v, w2, a2[co]);
                    a3[co] = fmaf(x3v, w0, a3[co]);
                    a3[co] = fmaf(x4v, w1, a3[co]);
                    a3[co] = fmaf(x5v, w2, a3[co]);
                }
            }
        }

        if (pre) {
            float2* nb = (float2*)&buf[cur ^ 1][0];
            nb[t + 0 * 256] = r0; nb[t + 1 * 256] = r1;
            nb[t + 2 * 256] = r2; nb[t + 3 * 256] = r3;
            if (tail) nb[t + 4 * 256] = r4;
        }
    }

    // ---- fused 2x2x2 maxpool + sum, entirely via in-wave shuffles ----
    float psum = 0.f;
    #pragma unroll
    for (int co = 0; co < COH; ++co) {
        float m0 = fmaxf(a0[co], a1[co]);
        float m1 = fmaxf(a2[co], a3[co]);
        m0 = fmaxf(m0, __shfl_xor(m0, 16));  // d-pool
        m1 = fmaxf(m1, __shfl_xor(m1, 16));
        m0 = fmaxf(m0, __shfl_xor(m0, 32));  // h-pool
        m1 = fmaxf(m1, __shfl_xor(m1, 32));
        psum += m0 + m1;
    }
    if ((t & 48) != 0) psum = 0.f;           // one owner per 2x2x2 block

    // block reduction -> one atomic per block
    #pragma unroll
    for (int off = 1; off < 64; off <<= 1) psum += __shfl_xor(psum, off);
    if ((t & 63) == 0) wsum[t >> 6] = psum;
    __syncthreads();
    if (t == 0) {
        float tot = (wsum[0] + wsum[1]) + (wsum[2] + wsum[3]);
        atomicAdd(&out[b], 0.5f * tot);
    }
}

// ---------------------------------------------------------------------------
extern "C" void kernel_launch(void* const* d_in, const int* in_sizes, int n_in,
                              void* d_out, int out_size, void* d_ws, size_t ws_size,
                              hipStream_t stream) {
    const float* x         = (const float*)d_in[0];
    const float* conv_w    = (const float*)d_in[1];
    const float* conv_bias = (const float*)d_in[2];
    const float* bias      = (const float*)d_in[3];
    float* out = (float*)d_out;
    float* wtb = (float*)d_ws;              // 13824 floats = 55.3 KB scratch

    wtrans_kernel<<<(NW + 255) / 256, 256, 0, stream>>>(conv_w, wtb);
    init_out_kernel<<<1, 64, 0, stream>>>(conv_bias, bias, out);
    conv_pool_kernel<<<dim3(16, 64, 4), 256, 0, stream>>>(x, wtb, out);
}